// Round 1
// baseline (271.683 us; speedup 1.0000x reference)
//
#include <hip/hip_runtime.h>

#define NW    16
#define NEUR  128
#define NPTS  65536
#define SIGMA 0.02f
#define U_MEAN 0.0f
#define U_SD   1.0f

#define TILE   128          // points per block
#define NTHR   512          // 8 waves
#define HPAD   136          // padded LDS row stride in halves (+8 -> 4-bank skew, 2-way max)
#define WMAT_HALVES (NEUR*HPAD)           // 17408 halves = 34816 B per weight matrix
#define WT_TOTAL (2*NW*WMAT_HALVES)       // 557056 halves = 1,114,112 B in d_ws

typedef _Float16 half8 __attribute__((ext_vector_type(8)));
typedef float    f32x4 __attribute__((ext_vector_type(4)));

__device__ __forceinline__ float tanh_fast(float x) {
    // tanh(x) = 1 - 2/(1+exp(2x)); exp->inf / ->0 saturate correctly to +-1
    float e = __expf(2.0f * x);
    return 1.0f - 2.0f * __builtin_amdgcn_rcpf(1.0f + e);
}

// W_hid fp32 [l][w][d][e]  ->  wt fp16 [(l*NW+w)][e][HPAD]  (transposed so k=d is contiguous, padded)
__global__ void prep_kernel(const float* __restrict__ W_hid, _Float16* __restrict__ wt) {
    int idx  = blockIdx.x * 256 + threadIdx.x;     // grid sized exactly: 2176*256 = 557056
    int d    = idx % HPAD;
    int rest = idx / HPAD;
    int e    = rest & (NEUR - 1);
    int lw   = rest >> 7;
    _Float16 v = (_Float16)0.0f;
    if (d < NEUR) v = (_Float16)W_hid[(lw * NEUR + d) * NEUR + e];
    wt[idx] = v;
}

// one hidden layer GEMM: acc[c] (16x16 tile c) = Hlds[128x128] @ Wlds^T fragment math
__device__ __forceinline__ void gemm_tile(const _Float16* Hbase, const _Float16* Wbase,
                                          int row0, int m, int q, f32x4 acc[8]) {
    const f32x4 z = {0.f, 0.f, 0.f, 0.f};
#pragma unroll
    for (int c = 0; c < 8; ++c) acc[c] = z;
#pragma unroll
    for (int s = 0; s < 4; ++s) {
        half8 a = *(const half8*)(Hbase + (row0 + m) * HPAD + s * 32 + q * 8);
#pragma unroll
        for (int c = 0; c < 8; ++c) {
            half8 b = *(const half8*)(Wbase + (c * 16 + m) * HPAD + s * 32 + q * 8);
            acc[c] = __builtin_amdgcn_mfma_f32_16x16x32_f16(a, b, acc[c], 0, 0, 0);
        }
    }
}

__device__ __forceinline__ void act_store(_Float16* Hbase, const float* __restrict__ bias,
                                          int row0, int m, int q, const f32x4 acc[8]) {
#pragma unroll
    for (int c = 0; c < 8; ++c) {
        float b = bias[c * 16 + m];
#pragma unroll
        for (int r = 0; r < 4; ++r) {
            // C/D layout: col = lane&15 (=m), row = q*4 + r
            Hbase[(row0 + q * 4 + r) * HPAD + c * 16 + m] = (_Float16)tanh_fast(acc[c][r] + b);
        }
    }
}

__device__ __forceinline__ void stage_w(const float4* __restrict__ g, float4* l4, int t) {
    float4 r0 = g[t], r1 = g[t + 512], r2 = g[t + 1024], r3 = g[t + 1536];
    float4 r4;
    if (t < 128) r4 = g[t + 2048];
    l4[t] = r0; l4[t + 512] = r1; l4[t + 1024] = r2; l4[t + 1536] = r3;
    if (t < 128) l4[t + 2048] = r4;
}

__global__ __launch_bounds__(NTHR, 4) void fbpinn_kernel(
    const float* __restrict__ x,     const float* __restrict__ means,
    const float* __restrict__ stds,  const float* __restrict__ mids,
    const float* __restrict__ W_in,  const float* __restrict__ b_in,
    const float* __restrict__ b_hid, const float* __restrict__ W_out,
    const float* __restrict__ b_out, const _Float16* __restrict__ wt,
    float* __restrict__ out)
{
    __shared__ __align__(16) _Float16 Wlds[WMAT_HALVES];   // 34816 B
    __shared__ __align__(16) _Float16 Hlds[TILE * HPAD];   // 34816 B
    __shared__ float xs[TILE];
    __shared__ float wouts[NEUR];
    __shared__ float red[4 * TILE];

    const int t    = threadIdx.x;
    const int blk  = blockIdx.x;
    const int lane = t & 63;
    const int wave = t >> 6;
    const int m    = lane & 15;        // MFMA col / A-row lane index
    const int q    = lane >> 4;        // MFMA quad
    const int row0 = wave * 16;        // this wave's 16-point slab
    const int p    = t & 127;          // point owned in elementwise phases
    const int qq   = t >> 7;           // neuron quarter in elementwise phases

    if (t < TILE) xs[t] = x[blk * TILE + t];
    float uacc = 0.f;
    f32x4 acc[8];

    for (int w = 0; w < NW; ++w) {
        __syncthreads();   // Hlds/red/wouts free from previous window

        // stage W(layer0) + W_out; compute layer 0 (1->128) in fp32
        stage_w((const float4*)(wt + (size_t)(0 * NW + w) * WMAT_HALVES), (float4*)Wlds, t);
        if (t < NEUR) wouts[t] = W_out[w * NEUR + t];

        const float xn = (xs[p] - means[w]) * __builtin_amdgcn_rcpf(stds[w]);
        const float* win = W_in + w * NEUR;
        const float* bin = b_in + w * NEUR;
        _Float16* hrow = &Hlds[p * HPAD + qq * 32];
#pragma unroll
        for (int i = 0; i < 32; i += 4) {
            float4 wv = *(const float4*)&win[qq * 32 + i];
            float4 bv = *(const float4*)&bin[qq * 32 + i];
            hrow[i + 0] = (_Float16)tanh_fast(fmaf(xn, wv.x, bv.x));
            hrow[i + 1] = (_Float16)tanh_fast(fmaf(xn, wv.y, bv.y));
            hrow[i + 2] = (_Float16)tanh_fast(fmaf(xn, wv.z, bv.z));
            hrow[i + 3] = (_Float16)tanh_fast(fmaf(xn, wv.w, bv.w));
        }
        __syncthreads();   // h1, W0, wouts visible

        gemm_tile(Hlds, Wlds, row0, m, q, acc);          // z2 = h1 @ W0
        __syncthreads();   // all LDS reads of GEMM1 done

        stage_w((const float4*)(wt + (size_t)(1 * NW + w) * WMAT_HALVES), (float4*)Wlds, t);
        act_store(Hlds, b_hid + (0 * NW + w) * NEUR, row0, m, q, acc);   // h2
        __syncthreads();

        gemm_tile(Hlds, Wlds, row0, m, q, acc);          // z3 = h2 @ W1
        __syncthreads();

        act_store(Hlds, b_hid + (1 * NW + w) * NEUR, row0, m, q, acc);   // h3
        __syncthreads();

        // epilogue: out_p = h3 . W_out + b_out ; acc += window(x_p) * out_p
        float sum = 0.f;
#pragma unroll
        for (int i = 0; i < 32; i += 8) {
            half8 hv = *(const half8*)&Hlds[p * HPAD + qq * 32 + i];
#pragma unroll
            for (int j = 0; j < 8; ++j)
                sum = fmaf((float)hv[j], wouts[qq * 32 + i + j], sum);
        }
        red[qq * TILE + p] = sum;
        __syncthreads();

        if (t < TILE) {
            float z  = red[t] + red[TILE + t] + red[2 * TILE + t] + red[3 * TILE + t] + b_out[w];
            float u  = z * U_SD + U_MEAN;
            float xv = xs[t];
            float xl = (xv - mids[w])     * (1.0f / SIGMA);
            float xr = (xv - mids[w + 1]) * (1.0f / SIGMA);
            float wf = __builtin_amdgcn_rcpf(1.0f + __expf(xl)) *
                       __builtin_amdgcn_rcpf(1.0f + __expf(-xr));
            uacc = fmaf(wf, u, uacc);
        }
    }

    if (t < TILE) out[blk * TILE + t] = uacc;
}

extern "C" void kernel_launch(void* const* d_in, const int* in_sizes, int n_in,
                              void* d_out, int out_size, void* d_ws, size_t ws_size,
                              hipStream_t stream) {
    const float* x     = (const float*)d_in[0];
    const float* means = (const float*)d_in[1];
    const float* stds  = (const float*)d_in[2];
    const float* mids  = (const float*)d_in[3];
    const float* W_in  = (const float*)d_in[4];
    const float* b_in  = (const float*)d_in[5];
    const float* W_hid = (const float*)d_in[6];
    const float* b_hid = (const float*)d_in[7];
    const float* W_out = (const float*)d_in[8];
    const float* b_out = (const float*)d_in[9];
    float* out = (float*)d_out;
    _Float16* wt = (_Float16*)d_ws;    // needs 1,114,112 B of scratch

    prep_kernel<<<WT_TOTAL / 256, 256, 0, stream>>>(W_hid, wt);
    fbpinn_kernel<<<NPTS / TILE, NTHR, 0, stream>>>(
        x, means, stds, mids, W_in, b_in, b_hid, W_out, b_out, wt, out);
}